// Round 2
// baseline (127.665 us; speedup 1.0000x reference)
//
#include <hip/hip_runtime.h>
#include <cstdint>
#include <cstddef>

#define J 64
#define XD 512
#define HD 1024
#define YD 16
#define PP 8
#define NN 1024

typedef __bf16 bf16;
typedef __attribute__((ext_vector_type(8))) __bf16 bf16x8;
typedef __attribute__((ext_vector_type(4))) __bf16 bf16x4;
typedef __attribute__((ext_vector_type(4))) float f32x4;

// ---------------- workspace layout (bytes) ----------------
// W1T : J*HD*XD bf16  = 67108864   @ 0
// W2T : J*YD*HD bf16  =  2097152   @ 67108864
// XBF : NN*XD   bf16  =  1048576   @ 69206016
// B1W : J*HD    f32   =   262144   @ 70254592
// B2W : J*YD    f32   =     4096   @ 70516736
// total = 70520832

__device__ __forceinline__ void gload16(const void* g, void* l) {
  __builtin_amdgcn_global_load_lds((__attribute__((address_space(1))) void*)(g),
                                   (__attribute__((address_space(3))) void*)(l),
                                   16, 0, 0);
}

// ---- K1a: W1T[j][h][x] = bf16(mu_W1[x][h] + e_W1[j][x][h]*sig_W1[x][h])
__global__ __launch_bounds__(256) void build_w1t(
    const float* __restrict__ muW1, const float* __restrict__ sigW1,
    const float* __restrict__ eW1, bf16* __restrict__ W1T) {
  __shared__ bf16 sT[64][66];  // [h-local][x-local], pad 66 for bank spread
  int b = blockIdx.x;
  int j = b >> 7;           // 128 tiles per j (8 x-tiles x 16 h-tiles)
  int xt = (b >> 4) & 7;
  int ht = b & 15;
  int x0 = xt << 6, h0 = ht << 6;
  int tid = threadIdx.x;
  int rp = tid >> 4;          // 0..15
  int cp = (tid & 15) << 2;   // 0..60
  const float* eB = eW1 + (size_t)j * (XD * HD);
#pragma unroll
  for (int p = 0; p < 4; ++p) {
    int x = rp + (p << 4);
    size_t gi = (size_t)(x0 + x) * HD + (h0 + cp);
    f32x4 e = *(const f32x4*)(eB + gi);
    f32x4 m = *(const f32x4*)(muW1 + gi);
    f32x4 s = *(const f32x4*)(sigW1 + gi);
#pragma unroll
    for (int i = 0; i < 4; ++i) sT[cp + i][x] = (bf16)(m[i] + e[i] * s[i]);
  }
  __syncthreads();
#pragma unroll
  for (int p = 0; p < 4; ++p) {
    int h = rp + (p << 4);
    bf16x4 v;
#pragma unroll
    for (int i = 0; i < 4; ++i) v[i] = sT[h][cp + i];
    *(bf16x4*)(W1T + (size_t)(j * HD + h0 + h) * XD + (x0 + cp)) = v;
  }
}

// ---- K1b: XBF, W2T, B1W, B2W
__global__ __launch_bounds__(256) void build_small(
    const float* __restrict__ x,
    const float* __restrict__ muW2, const float* __restrict__ sigW2,
    const float* __restrict__ eW2,
    const float* __restrict__ mub1, const float* __restrict__ sigb1,
    const float* __restrict__ eb1,
    const float* __restrict__ mub2, const float* __restrict__ sigb2,
    const float* __restrict__ eb2,
    bf16* __restrict__ XBF, bf16* __restrict__ W2T,
    float* __restrict__ B1W, float* __restrict__ B2W) {
  int i = blockIdx.x * 256 + threadIdx.x;
  const int c0 = NN * XD;        // 524288
  const int c1 = J * YD * HD;    // 1048576
  const int c2 = J * HD;         // 65536
  const int c3 = J * YD;         // 1024
  if (i < c0) { XBF[i] = (bf16)x[i]; return; }
  i -= c0;
  if (i < c1) {
    // W2T[(j*16+y)*1024 + h]
    int h = i & (HD - 1);
    int jy = i >> 10;
    int y = jy & 15;
    int j = jy >> 4;
    float mu = muW2[h * YD + y], sg = sigW2[h * YD + y];
    float e = eW2[((size_t)j * HD + h) * YD + y];
    W2T[i] = (bf16)(mu + e * sg);
    return;
  }
  i -= c1;
  if (i < c2) {
    int h = i & (HD - 1);
    B1W[i] = mub1[h] + eb1[i] * sigb1[h];
    return;
  }
  i -= c2;
  if (i < c3) {
    int y = i & 15;
    B2W[i] = mub2[y] + eb2[i] * sigb2[y];
  }
}

// ---- K2: fused GEMM1 + clip + GEMM2 + permutation scatter
// block = (j, 128-row n tile); 256 threads = 4 waves (2x2 over 128x128 GEMM1 tile)
__global__ __launch_bounds__(256, 2) void fused_mlp(
    const bf16* __restrict__ XBF, const bf16* __restrict__ W1T,
    const bf16* __restrict__ W2T, const float* __restrict__ B1W,
    const float* __restrict__ B2W, const float* __restrict__ permu,
    float* __restrict__ out) {
  extern __shared__ char smem[];          // 65536 bytes
  bf16* sA = (bf16*)smem;                 // [128][64] bf16, 16KB, XOR-swizzled
  bf16* sB = (bf16*)(smem + 16384);       // [128][64] bf16, 16KB, XOR-swizzled
  bf16* sH = (bf16*)(smem + 32768);       // [128][128] bf16, 32KB, XOR-swizzled
  float* sOut = (float*)smem;             // [128][17] f32 (overlaps sA, epilogue only)
  int* sIdx = (int*)(smem + 16384);       // [128] (overlaps sB, epilogue only)

  int b = blockIdx.x;
  int L = ((b & 7) << 6) + (b >> 3);      // XCD swizzle, bijective (512 = 8*64)
  int j = L >> 3;
  int n0 = (L & 7) << 7;

  int tid = threadIdx.x;
  int wid = tid >> 6;
  int lane = tid & 63;
  int l15 = lane & 15;
  int lg = lane >> 4;               // 0..3
  int wr = (wid >> 1) << 6;         // wave n offset (GEMM1)
  int wc = (wid & 1) << 6;          // wave h offset (GEMM1)
  int srow = (wid << 3) + (lane >> 3);  // staging row 0..31 (+32/pass)
  int sslot = lane & 7;                 // staging 16B slot in 128B row

  f32x4 acc2[2];
#pragma unroll
  for (int f = 0; f < 2; ++f)
#pragma unroll
    for (int r = 0; r < 4; ++r) acc2[f][r] = 0.0f;

  const bf16* w1base = W1T + (size_t)j * HD * XD;
  const bf16* w2g = W2T + (size_t)((j << 4) + l15) * HD;  // row y = l15

#pragma unroll 1
  for (int hb = 0; hb < HD / 128; ++hb) {
    f32x4 acc1[4][4];
#pragma unroll
    for (int fa = 0; fa < 4; ++fa)
#pragma unroll
      for (int fb = 0; fb < 4; ++fb)
#pragma unroll
        for (int r = 0; r < 4; ++r) acc1[fa][fb][r] = 0.0f;

#pragma unroll 1
    for (int ks = 0; ks < XD / 64; ++ks) {
      int k0 = ks << 6;
      __syncthreads();  // protect sA/sB from overwrite while waves still read
      // stage sA (x tile) + sB (W1T tile): linear LDS dest, pre-swizzled source
#pragma unroll
      for (int p = 0; p < 4; ++p) {
        int r = (p << 5) + srow;
        int sc = sslot ^ (r & 7);
        gload16(XBF + (size_t)(n0 + r) * XD + k0 + (sc << 3),
                (char*)sA + (p << 12) + (wid << 10));
        gload16(w1base + (size_t)((hb << 7) + r) * XD + k0 + (sc << 3),
                (char*)sB + (p << 12) + (wid << 10));
      }
      __syncthreads();  // drains vmcnt (gload_lds) per compiler barrier semantics
#pragma unroll
      for (int kk = 0; kk < 2; ++kk) {
        bf16x8 af[4], bg[4];
#pragma unroll
        for (int f = 0; f < 4; ++f) {
          int ra = wr + (f << 4) + l15;
          int ca = ((kk << 6) + (lg << 4)) ^ ((ra & 7) << 4);
          af[f] = *(const bf16x8*)((char*)sA + (ra << 7) + ca);
          int rb = wc + (f << 4) + l15;
          int cb = ((kk << 6) + (lg << 4)) ^ ((rb & 7) << 4);
          bg[f] = *(const bf16x8*)((char*)sB + (rb << 7) + cb);
        }
#pragma unroll
        for (int fa = 0; fa < 4; ++fa)
#pragma unroll
          for (int fb = 0; fb < 4; ++fb)
            acc1[fa][fb] = __builtin_amdgcn_mfma_f32_16x16x32_bf16(
                af[fa], bg[fb], acc1[fa][fb], 0, 0, 0);
      }
    }
    // ---- b1 + hardtanh -> sH (swizzled [n][h] bf16)
    float b1v[4];
#pragma unroll
    for (int fb = 0; fb < 4; ++fb)
      b1v[fb] = B1W[j * HD + (hb << 7) + wc + (fb << 4) + l15];
#pragma unroll
    for (int fa = 0; fa < 4; ++fa) {
#pragma unroll
      for (int fb = 0; fb < 4; ++fb) {
        int col = wc + (fb << 4) + l15;
#pragma unroll
        for (int r = 0; r < 4; ++r) {
          int row = wr + (fa << 4) + (lg << 2) + r;
          float v = acc1[fa][fb][r] + b1v[fb];
          v = fminf(1.0f, fmaxf(-1.0f, v));
          int byte = (row << 8) + (((col << 1)) ^ ((row & 7) << 4));
          *(bf16*)((char*)sH + byte) = (bf16)v;
        }
      }
    }
    __syncthreads();  // sH complete before GEMM2 reads
    // ---- GEMM2: wave owns rows wid*32..+32; B-frags straight from global (L2-hot)
#pragma unroll
    for (int kk = 0; kk < 4; ++kk) {
      bf16x8 wg = *(const bf16x8*)(w2g + (hb << 7) + (kk << 5) + (lg << 3));
#pragma unroll
      for (int f = 0; f < 2; ++f) {
        int row = (wid << 5) + (f << 4) + l15;
        int cb = ((kk << 6) + (lg << 4)) ^ ((row & 7) << 4);
        bf16x8 hf = *(const bf16x8*)((char*)sH + (row << 8) + cb);
        acc2[f] = __builtin_amdgcn_mfma_f32_16x16x32_bf16(hf, wg, acc2[f], 0, 0, 0);
      }
    }
  }
  // ---- epilogue: b2, stage out tile, permutation gather, coalesced store
  float b2v = B2W[(j << 4) + l15];
#pragma unroll
  for (int f = 0; f < 2; ++f)
#pragma unroll
    for (int r = 0; r < 4; ++r) {
      int row = (wid << 5) + (f << 4) + (lg << 2) + r;
      sOut[row * 17 + l15] = acc2[f][r] + b2v;
    }
  if (tid < 128) {  // cidx[p][y] = c with permu[p][c][y]==1
    int p = tid >> 4, y = tid & 15;
    int c = 0;
#pragma unroll
    for (int cc = 0; cc < 16; ++cc)
      if (permu[((p << 4) + cc) * 16 + y] > 0.5f) c = cc;
    sIdx[tid] = c;
  }
  __syncthreads();
#pragma unroll 1
  for (int it = 0; it < 16; ++it) {
    int flat = (it << 10) + (tid << 2);   // p[3] n[7] y[4]
    int p = flat >> 11;
    int n = (flat >> 4) & 127;
    int y0 = flat & 15;
    f32x4 v;
#pragma unroll
    for (int q = 0; q < 4; ++q) v[q] = sOut[n * 17 + sIdx[(p << 4) + y0 + q]];
    *(f32x4*)(out + ((size_t)((j << 3) + p) * NN + n0 + n) * YD + y0) = v;
  }
}

extern "C" void kernel_launch(void* const* d_in, const int* in_sizes, int n_in,
                              void* d_out, int out_size, void* d_ws, size_t ws_size,
                              hipStream_t stream) {
  (void)in_sizes; (void)n_in; (void)out_size; (void)ws_size;
  const float* x      = (const float*)d_in[0];
  const float* mu_W1  = (const float*)d_in[1];
  const float* mu_b1  = (const float*)d_in[2];
  const float* mu_W2  = (const float*)d_in[3];
  const float* mu_b2  = (const float*)d_in[4];
  const float* sig_W1 = (const float*)d_in[5];
  const float* sig_b1 = (const float*)d_in[6];
  const float* sig_W2 = (const float*)d_in[7];
  const float* sig_b2 = (const float*)d_in[8];
  const float* e_W1   = (const float*)d_in[9];
  const float* e_b1   = (const float*)d_in[10];
  const float* e_W2   = (const float*)d_in[11];
  const float* e_b2   = (const float*)d_in[12];
  const float* permu  = (const float*)d_in[13];
  float* out = (float*)d_out;

  char* ws = (char*)d_ws;
  bf16* W1T = (bf16*)(ws);
  bf16* W2T = (bf16*)(ws + 67108864);
  bf16* XBF = (bf16*)(ws + 69206016);
  float* B1W = (float*)(ws + 70254592);
  float* B2W = (float*)(ws + 70516736);

  build_w1t<<<dim3(8192), dim3(256), 0, stream>>>(mu_W1, sig_W1, e_W1, W1T);
  build_small<<<dim3(6404), dim3(256), 0, stream>>>(
      x, mu_W2, sig_W2, e_W2, mu_b1, sig_b1, e_b1, mu_b2, sig_b2, e_b2,
      XBF, W2T, B1W, B2W);
  fused_mlp<<<dim3(512), dim3(256), 65536, stream>>>(
      XBF, W1T, W2T, B1W, B2W, permu, out);
}